// Round 10
// baseline (177.798 us; speedup 1.0000x reference)
//
#include <hip/hip_runtime.h>
#include <cfloat>
#include <cstdint>

#define NPTS 65536
#define DIM 256
#define NC 16
#define KSEL 2048
#define VMAX 4608
#define EPSV 1e-6f

// ws layout (bytes):
//     0 : float sums[16*256]   (16384)  -- dim-interleaved: [c][j*64+m] = dim 4m+j
// 16384 : int counts[16]       (64)
// 16512 : int offsets[16]      (64)
// 16576 : float csq[16]        (64)
// 16640 : float pos_stat[16]   (64)
// 16704 : float neg_stat[256]  (1024)
// 17728 : float centers[4096]  (16384)
// 34112 : int bhist[256*16]    (16384)
// 65536 : float Dmat[16*65536] (4 MB)

// One wave per row: lane m loads float4 dims [4m,4m+4). LDS accumulate via
// ds float atomics into interleaved layout (stride-1 per lane, conflict-free).
__global__ void __launch_bounds__(256) k_accum(const float* __restrict__ x,
                                               const int* __restrict__ y,
                                               float* __restrict__ gsums,
                                               int* __restrict__ gcounts) {
  __shared__ float lsum[NC * DIM];
  __shared__ int labs[64];
  int tid = threadIdx.x;
  for (int u = tid; u < NC * DIM; u += 256) lsum[u] = 0.f;
  int n0 = blockIdx.x * 64;
  if (tid < 64) labs[tid] = y[(n0 + tid) * 3 + 2];
  __syncthreads();

  int w = tid >> 6;   // wave 0..3
  int m = tid & 63;   // lane
#pragma unroll
  for (int r0 = 0; r0 < 64; r0 += 4) {
    int r = r0 + w;
    float4 xv = *(const float4*)(x + (size_t)(n0 + r) * DIM + m * 4);
    int base = labs[r] * DIM + m;
    atomicAdd(&lsum[base], xv.x);
    atomicAdd(&lsum[base + 64], xv.y);
    atomicAdd(&lsum[base + 128], xv.z);
    atomicAdd(&lsum[base + 192], xv.w);
  }
  __syncthreads();
  if (tid < NC) {
    int c = 0;
    for (int r = 0; r < 64; ++r) c += (labs[r] == tid);
    atomicAdd(&gcounts[tid], c);
  }
  for (int u = tid; u < NC * DIM; u += 256) atomicAdd(&gsums[u], lsum[u]);
}

__global__ void __launch_bounds__(256) k_centers(const float* __restrict__ gsums,
                                                 const int* __restrict__ gcounts,
                                                 float* __restrict__ centers,
                                                 float* __restrict__ csq,
                                                 int* __restrict__ offsets) {
  __shared__ float red[DIM];
  int d = threadIdx.x;
  int dperm = (d & 3) * 64 + (d >> 2);  // inverse of interleaved layout
  float v[NC];
#pragma unroll
  for (int c = 0; c < NC; ++c) {
    v[c] = gsums[c * DIM + dperm] / (float)gcounts[c] + EPSV;
    centers[c * DIM + d] = v[c];
  }
#pragma unroll 1
  for (int c = 0; c < NC; ++c) {
    red[d] = v[c] * v[c];
    __syncthreads();
    for (int st = 128; st > 0; st >>= 1) {
      if (d < st) red[d] += red[d + st];
      __syncthreads();
    }
    if (d == 0) csq[c] = red[0];
    __syncthreads();
  }
  if (d == 0) {
    int run = 0;
    for (int c = 0; c < NC; ++c) { offsets[c] = run; run += gcounts[c]; }
  }
}

__global__ void __launch_bounds__(256) k_hist(const int* __restrict__ y,
                                              int* __restrict__ bhist) {
  __shared__ int h[NC];
  int t = threadIdx.x;
  if (t < NC) h[t] = 0;
  __syncthreads();
  int p = blockIdx.x * 256 + t;
  atomicAdd(&h[y[p * 3 + 2]], 1);
  __syncthreads();
  if (t < NC) bhist[blockIdx.x * NC + t] = h[t];
}

__global__ void __launch_bounds__(256) k_scan(const int* __restrict__ offsets,
                                              int* __restrict__ bhist) {
  __shared__ int lh[256 * NC];
  __shared__ int segbase[16][NC];
  int t = threadIdx.x;
  for (int u = t; u < 256 * NC; u += 256) lh[u] = bhist[u];
  __syncthreads();
  int c = t & 15, g = t >> 4;
  int part = 0;
#pragma unroll
  for (int b = 0; b < 16; ++b) part += lh[(g * 16 + b) * NC + c];
  segbase[g][c] = part;
  __syncthreads();
  if (t < NC) {
    int run = offsets[t];
#pragma unroll
    for (int g2 = 0; g2 < 16; ++g2) { int tmp = segbase[g2][t]; segbase[g2][t] = run; run += tmp; }
  }
  __syncthreads();
  int run = segbase[g][c];
#pragma unroll
  for (int b = 0; b < 16; ++b) {
    int idx = (g * 16 + b) * NC + c;
    int tmp = lh[idx]; lh[idx] = run; run += tmp;
  }
  __syncthreads();
  for (int u = t; u < 256 * NC; u += 256) bhist[u] = lh[u];
}

__global__ void __launch_bounds__(256) k_dist(const float* __restrict__ x,
                                              const int* __restrict__ y,
                                              const float* __restrict__ centers,
                                              const float* __restrict__ csq,
                                              const int* __restrict__ bbase,
                                              float* __restrict__ Dmat) {
  __shared__ float4 cc[NC * 64];
  __shared__ float csql[NC];
  __shared__ int labs[256];
  int t = threadIdx.x;
  const float4* cptr = (const float4*)centers;
  for (int u = t; u < NC * 64; u += 256) {
    int q = u & 63;
    int qs = (q & 0x38) | ((q & 7) ^ ((q >> 3) & 7));
    cc[(u & ~63) | qs] = cptr[u];
  }
  if (t < NC) csql[t] = csq[t];
  int chunk = blockIdx.x >> 3;
  int sub = blockIdx.x & 7;
  labs[t] = y[(chunk * 256 + t) * 3 + 2];
  __syncthreads();

  int pl = sub * 32 + (t >> 3);
  int p = chunk * 256 + pl;
  int s = t & 7;
  const float4* xp = (const float4*)(x + (size_t)p * DIM) + s * 8;
  float4 xv[8];
#pragma unroll
  for (int j = 0; j < 8; ++j) xv[j] = xp[j];
  float xsq = 0.f;
#pragma unroll
  for (int j = 0; j < 8; ++j)
    xsq += xv[j].x * xv[j].x + xv[j].y * xv[j].y + xv[j].z * xv[j].z + xv[j].w * xv[j].w;

  float acc[NC];
#pragma unroll
  for (int i = 0; i < NC; ++i) acc[i] = 0.f;
#pragma unroll
  for (int i = 0; i < NC; ++i) {
#pragma unroll
    for (int j = 0; j < 8; ++j) {
      float4 cv = cc[i * 64 + s * 8 + (j ^ s)];
      acc[i] += xv[j].x * cv.x + xv[j].y * cv.y + xv[j].z * cv.z + xv[j].w * cv.w;
    }
  }

#pragma unroll
  for (int m = 1; m < 8; m <<= 1) {
    xsq += __shfl_xor(xsq, m);
#pragma unroll
    for (int i = 0; i < NC; ++i) acc[i] += __shfl_xor(acc[i], m);
  }

  if (s == 0) {
    int lab = labs[pl];
    int rank = 0;
    for (int q = 0; q < pl; ++q) rank += (labs[q] == lab);
    int base = bbase[chunk * NC + lab] + rank;
#pragma unroll
    for (int i = 0; i < NC; ++i) {
      float d2 = csql[i] - 2.f * acc[i] + xsq;
      Dmat[(size_t)i * NPTS + base] = sqrtf(fmaxf(d2, 0.f));
    }
  }
}

// Radix-select (exact K-th order statistic via 11+11+10-bit LDS histograms),
// then two-pass mean/var over {key < T} + exact-tie correction.
__global__ void __launch_bounds__(512) k_select(const float* __restrict__ Dmat,
                                                const int* __restrict__ gcounts,
                                                const int* __restrict__ offsets,
                                                float* __restrict__ pos_stat,
                                                float* __restrict__ neg_stat) {
  __shared__ unsigned int keys[VMAX];
  __shared__ int hist[2048];
  __shared__ int sc[512];
  __shared__ float fred[512];
  __shared__ int bsel[2];
  int tid = threadIdx.x;
  int b = blockIdx.x;
  int ci = b >> 4, cl = b & 15;
  bool largest = (ci == cl);
  int cnt = gcounts[cl];
  if (cnt > VMAX) cnt = VMAX;
  int off = offsets[cl];
  const float* src = Dmat + (size_t)ci * NPTS + off;
  unsigned int inv = largest ? 0xFFFFFFFFu : 0u;
  for (int t = tid; t < cnt; t += 512) keys[t] = __float_as_uint(src[t]) ^ inv;
  __syncthreads();

  int target = KSEL;
  unsigned int pfx = 0;

  // ---- Level A: bits [21,32) ----
  for (int u = tid; u < 2048; u += 512) hist[u] = 0;
  __syncthreads();
  for (int t = tid; t < cnt; t += 512) atomicAdd(&hist[keys[t] >> 21], 1);
  __syncthreads();
  {
    int segsum = 0;
#pragma unroll
    for (int j = 0; j < 4; ++j) segsum += hist[tid * 4 + j];
    sc[tid] = segsum; __syncthreads();
    for (int ofs = 1; ofs < 512; ofs <<= 1) {
      int v = (tid >= ofs) ? sc[tid - ofs] : 0; __syncthreads();
      sc[tid] += v; __syncthreads();
    }
    int incl = sc[tid], excl = incl - segsum;
    if (excl < target && target <= incl) {
      int run = excl;
      for (int j = 0; j < 4; ++j) {
        int h = hist[tid * 4 + j];
        if (run < target && target <= run + h) { bsel[0] = tid * 4 + j; bsel[1] = target - run; }
        run += h;
      }
    }
    __syncthreads();
    pfx = ((unsigned int)bsel[0]) << 21; target = bsel[1];
  }
  __syncthreads();

  // ---- Level B: bits [10,21) ----
  for (int u = tid; u < 2048; u += 512) hist[u] = 0;
  __syncthreads();
  for (int t = tid; t < cnt; t += 512) {
    unsigned int k = keys[t];
    if ((k >> 21) == (pfx >> 21)) atomicAdd(&hist[(k >> 10) & 0x7FF], 1);
  }
  __syncthreads();
  {
    int segsum = 0;
#pragma unroll
    for (int j = 0; j < 4; ++j) segsum += hist[tid * 4 + j];
    sc[tid] = segsum; __syncthreads();
    for (int ofs = 1; ofs < 512; ofs <<= 1) {
      int v = (tid >= ofs) ? sc[tid - ofs] : 0; __syncthreads();
      sc[tid] += v; __syncthreads();
    }
    int incl = sc[tid], excl = incl - segsum;
    if (excl < target && target <= incl) {
      int run = excl;
      for (int j = 0; j < 4; ++j) {
        int h = hist[tid * 4 + j];
        if (run < target && target <= run + h) { bsel[0] = tid * 4 + j; bsel[1] = target - run; }
        run += h;
      }
    }
    __syncthreads();
    pfx |= ((unsigned int)bsel[0]) << 10; target = bsel[1];
  }
  __syncthreads();

  // ---- Level C: bits [0,10) ----
  for (int u = tid; u < 1024; u += 512) hist[u] = 0;
  __syncthreads();
  for (int t = tid; t < cnt; t += 512) {
    unsigned int k = keys[t];
    if ((k >> 10) == (pfx >> 10)) atomicAdd(&hist[k & 0x3FF], 1);
  }
  __syncthreads();
  {
    int segsum = hist[tid * 2] + hist[tid * 2 + 1];
    sc[tid] = segsum; __syncthreads();
    for (int ofs = 1; ofs < 512; ofs <<= 1) {
      int v = (tid >= ofs) ? sc[tid - ofs] : 0; __syncthreads();
      sc[tid] += v; __syncthreads();
    }
    int incl = sc[tid], excl = incl - segsum;
    if (excl < target && target <= incl) {
      int run = excl;
      for (int j = 0; j < 2; ++j) {
        int h = hist[tid * 2 + j];
        if (run < target && target <= run + h) { bsel[0] = tid * 2 + j; }
        run += h;
      }
    }
    __syncthreads();
  }
  unsigned int T = pfx | (unsigned int)bsel[0];
  float fT = __uint_as_float(T ^ inv);
  __syncthreads();

  int nl = 0; float sl = 0.f;
  for (int t = tid; t < cnt; t += 512) {
    unsigned int k = keys[t];
    if (k < T) { nl++; sl += __uint_as_float(k ^ inv); }
  }
  sc[tid] = nl; fred[tid] = sl; __syncthreads();
  for (int st = 256; st > 0; st >>= 1) {
    if (tid < st) { sc[tid] += sc[tid + st]; fred[tid] += fred[tid + st]; }
    __syncthreads();
  }
  int n_less = sc[0];
  float mean = (fred[0] + (float)(KSEL - n_less) * fT) / (float)KSEL;
  __syncthreads();

  float sv = 0.f;
  for (int t = tid; t < cnt; t += 512) {
    unsigned int k = keys[t];
    if (k < T) { float d = __uint_as_float(k ^ inv) - mean; sv += d * d; }
  }
  fred[tid] = sv; __syncthreads();
  for (int st = 256; st > 0; st >>= 1) {
    if (tid < st) fred[tid] += fred[tid + st];
    __syncthreads();
  }
  if (tid == 0) {
    float dT = fT - mean;
    float var = (fred[0] + (float)(KSEL - n_less) * dT * dT) / (float)(KSEL - 1);
    if (largest) pos_stat[ci] = mean + 1.96f * sqrtf(var);
    else neg_stat[ci * 16 + cl] = mean - 1.96f * sqrtf(var);
  }
}

__global__ void __launch_bounds__(256) k_loss(const float* __restrict__ pos_stat,
                                              const float* __restrict__ neg_stat,
                                              float* __restrict__ out) {
  __shared__ float red[256];
  int t = threadIdx.x;
  int i = t >> 4, c = t & 15;
  float v = 0.f;
  if (i != c) v = fmaxf(1.0f + pos_stat[i] - neg_stat[t], 0.f);
  red[t] = v; __syncthreads();
  for (int st = 128; st > 0; st >>= 1) { if (t < st) red[t] += red[t + st]; __syncthreads(); }
  if (t == 0) out[0] = red[0];
}

extern "C" void kernel_launch(void* const* d_in, const int* in_sizes, int n_in,
                              void* d_out, int out_size, void* d_ws, size_t ws_size,
                              hipStream_t stream) {
  const float* x = (const float*)d_in[0];
  const int* y = (const int*)d_in[1];
  float* out = (float*)d_out;
  char* ws = (char*)d_ws;

  float* sums = (float*)(ws + 0);
  int* counts = (int*)(ws + 16384);
  int* offsets = (int*)(ws + 16512);
  float* csq = (float*)(ws + 16576);
  float* pos_stat = (float*)(ws + 16640);
  float* neg_stat = (float*)(ws + 16704);
  float* centers = (float*)(ws + 17728);
  int* bhist = (int*)(ws + 34112);
  float* Dmat = (float*)(ws + 65536);

  hipMemsetAsync(ws, 0, 16512, stream);  // sums + counts
  k_accum<<<1024, 256, 0, stream>>>(x, y, sums, counts);
  k_centers<<<1, 256, 0, stream>>>(sums, counts, centers, csq, offsets);
  k_hist<<<256, 256, 0, stream>>>(y, bhist);
  k_scan<<<1, 256, 0, stream>>>(offsets, bhist);
  k_dist<<<2048, 256, 0, stream>>>(x, y, centers, csq, bhist, Dmat);
  k_select<<<256, 512, 0, stream>>>(Dmat, counts, offsets, pos_stat, neg_stat);
  k_loss<<<1, 256, 0, stream>>>(pos_stat, neg_stat, out);
}

// Round 11
// 116.978 us; speedup vs baseline: 1.5199x; 1.5199x over previous
//
#include <hip/hip_runtime.h>
#include <cfloat>
#include <cstdint>

#define NPTS 65536
#define DIM 256
#define NC 16
#define KSEL 2048
#define VMAX 4608
#define EPSV 1e-6f

// ws layout (bytes):
//     0 : float sums[16*256]   (16384)
// 16384 : int counts[16]       (64)
// 16512 : int offsets[16]      (64)
// 16576 : float csq[16]        (64)
// 16640 : float pos_stat[16]   (64)
// 16704 : float neg_stat[256]  (1024)
// 17728 : float centers[4096]  (16384)
// 34112 : int bhist[256*16]    (16384)
// 65536 : float Dmat[16*65536] (4 MB)

// Branch-free register accumulation: thread = dim, acc[16] in VGPRs,
// acc[c] += (lab==c) ? xv : 0 (statically unrolled). No LDS in inner loop.
__global__ void __launch_bounds__(256) k_accum(const float* __restrict__ x,
                                               const int* __restrict__ y,
                                               float* __restrict__ gsums,
                                               int* __restrict__ gcounts) {
  __shared__ int labs[64];
  int tid = threadIdx.x;
  int n0 = blockIdx.x * 64;
  if (tid < 64) labs[tid] = y[(n0 + tid) * 3 + 2];
  __syncthreads();

  float acc[NC];
#pragma unroll
  for (int c = 0; c < NC; ++c) acc[c] = 0.f;

#pragma unroll 4
  for (int r = 0; r < 64; ++r) {
    float xv = x[(size_t)(n0 + r) * DIM + tid];
    int lab = labs[r];
#pragma unroll
    for (int c = 0; c < NC; ++c) acc[c] += (lab == c) ? xv : 0.f;
  }

#pragma unroll
  for (int c = 0; c < NC; ++c) atomicAdd(&gsums[c * DIM + tid], acc[c]);
  if (tid < NC) {
    int cn = 0;
    for (int r = 0; r < 64; ++r) cn += (labs[r] == tid);
    atomicAdd(&gcounts[tid], cn);
  }
}

__global__ void __launch_bounds__(256) k_centers(const float* __restrict__ gsums,
                                                 const int* __restrict__ gcounts,
                                                 float* __restrict__ centers,
                                                 float* __restrict__ csq,
                                                 int* __restrict__ offsets) {
  __shared__ float red[DIM];
  int d = threadIdx.x;
  float v[NC];
#pragma unroll
  for (int c = 0; c < NC; ++c) {
    v[c] = gsums[c * DIM + d] / (float)gcounts[c] + EPSV;
    centers[c * DIM + d] = v[c];
  }
#pragma unroll 1
  for (int c = 0; c < NC; ++c) {
    red[d] = v[c] * v[c];
    __syncthreads();
    for (int st = 128; st > 0; st >>= 1) {
      if (d < st) red[d] += red[d + st];
      __syncthreads();
    }
    if (d == 0) csq[c] = red[0];
    __syncthreads();
  }
  if (d == 0) {
    int run = 0;
    for (int c = 0; c < NC; ++c) { offsets[c] = run; run += gcounts[c]; }
  }
}

__global__ void __launch_bounds__(256) k_hist(const int* __restrict__ y,
                                              int* __restrict__ bhist) {
  __shared__ int h[NC];
  int t = threadIdx.x;
  if (t < NC) h[t] = 0;
  __syncthreads();
  int p = blockIdx.x * 256 + t;
  atomicAdd(&h[y[p * 3 + 2]], 1);
  __syncthreads();
  if (t < NC) bhist[blockIdx.x * NC + t] = h[t];
}

__global__ void __launch_bounds__(256) k_scan(const int* __restrict__ offsets,
                                              int* __restrict__ bhist) {
  __shared__ int lh[256 * NC];
  __shared__ int segbase[16][NC];
  int t = threadIdx.x;
  for (int u = t; u < 256 * NC; u += 256) lh[u] = bhist[u];
  __syncthreads();
  int c = t & 15, g = t >> 4;
  int part = 0;
#pragma unroll
  for (int b = 0; b < 16; ++b) part += lh[(g * 16 + b) * NC + c];
  segbase[g][c] = part;
  __syncthreads();
  if (t < NC) {
    int run = offsets[t];
#pragma unroll
    for (int g2 = 0; g2 < 16; ++g2) { int tmp = segbase[g2][t]; segbase[g2][t] = run; run += tmp; }
  }
  __syncthreads();
  int run = segbase[g][c];
#pragma unroll
  for (int b = 0; b < 16; ++b) {
    int idx = (g * 16 + b) * NC + c;
    int tmp = lh[idx]; lh[idx] = run; run += tmp;
  }
  __syncthreads();
  for (int u = t; u < 256 * NC; u += 256) bhist[u] = lh[u];
}

__global__ void __launch_bounds__(256) k_dist(const float* __restrict__ x,
                                              const int* __restrict__ y,
                                              const float* __restrict__ centers,
                                              const float* __restrict__ csq,
                                              const int* __restrict__ bbase,
                                              float* __restrict__ Dmat) {
  __shared__ float4 cc[NC * 64];
  __shared__ float csql[NC];
  __shared__ int labs[256];
  int t = threadIdx.x;
  const float4* cptr = (const float4*)centers;
  for (int u = t; u < NC * 64; u += 256) {
    int q = u & 63;
    int qs = (q & 0x38) | ((q & 7) ^ ((q >> 3) & 7));
    cc[(u & ~63) | qs] = cptr[u];
  }
  if (t < NC) csql[t] = csq[t];
  int chunk = blockIdx.x >> 3;
  int sub = blockIdx.x & 7;
  labs[t] = y[(chunk * 256 + t) * 3 + 2];
  __syncthreads();

  int pl = sub * 32 + (t >> 3);
  int p = chunk * 256 + pl;
  int s = t & 7;
  const float4* xp = (const float4*)(x + (size_t)p * DIM) + s * 8;
  float4 xv[8];
#pragma unroll
  for (int j = 0; j < 8; ++j) xv[j] = xp[j];
  float xsq = 0.f;
#pragma unroll
  for (int j = 0; j < 8; ++j)
    xsq += xv[j].x * xv[j].x + xv[j].y * xv[j].y + xv[j].z * xv[j].z + xv[j].w * xv[j].w;

  float acc[NC];
#pragma unroll
  for (int i = 0; i < NC; ++i) acc[i] = 0.f;
#pragma unroll
  for (int i = 0; i < NC; ++i) {
#pragma unroll
    for (int j = 0; j < 8; ++j) {
      float4 cv = cc[i * 64 + s * 8 + (j ^ s)];
      acc[i] += xv[j].x * cv.x + xv[j].y * cv.y + xv[j].z * cv.z + xv[j].w * cv.w;
    }
  }

#pragma unroll
  for (int m = 1; m < 8; m <<= 1) {
    xsq += __shfl_xor(xsq, m);
#pragma unroll
    for (int i = 0; i < NC; ++i) acc[i] += __shfl_xor(acc[i], m);
  }

  if (s == 0) {
    int lab = labs[pl];
    int rank = 0;
    for (int q = 0; q < pl; ++q) rank += (labs[q] == lab);
    int base = bbase[chunk * NC + lab] + rank;
#pragma unroll
    for (int i = 0; i < NC; ++i) {
      float d2 = csql[i] - 2.f * acc[i] + xsq;
      Dmat[(size_t)i * NPTS + base] = sqrtf(fmaxf(d2, 0.f));
    }
  }
}

// Radix-select (exact K-th order statistic via 11+11+10-bit LDS histograms),
// then two-pass mean/var over {key < T} + exact-tie correction.
__global__ void __launch_bounds__(512) k_select(const float* __restrict__ Dmat,
                                                const int* __restrict__ gcounts,
                                                const int* __restrict__ offsets,
                                                float* __restrict__ pos_stat,
                                                float* __restrict__ neg_stat) {
  __shared__ unsigned int keys[VMAX];
  __shared__ int hist[2048];
  __shared__ int sc[512];
  __shared__ float fred[512];
  __shared__ int bsel[2];
  int tid = threadIdx.x;
  int b = blockIdx.x;
  int ci = b >> 4, cl = b & 15;
  bool largest = (ci == cl);
  int cnt = gcounts[cl];
  if (cnt > VMAX) cnt = VMAX;
  int off = offsets[cl];
  const float* src = Dmat + (size_t)ci * NPTS + off;
  unsigned int inv = largest ? 0xFFFFFFFFu : 0u;
  for (int t = tid; t < cnt; t += 512) keys[t] = __float_as_uint(src[t]) ^ inv;
  __syncthreads();

  int target = KSEL;
  unsigned int pfx = 0;

  // ---- Level A: bits [21,32) ----
  for (int u = tid; u < 2048; u += 512) hist[u] = 0;
  __syncthreads();
  for (int t = tid; t < cnt; t += 512) atomicAdd(&hist[keys[t] >> 21], 1);
  __syncthreads();
  {
    int segsum = 0;
#pragma unroll
    for (int j = 0; j < 4; ++j) segsum += hist[tid * 4 + j];
    sc[tid] = segsum; __syncthreads();
    for (int ofs = 1; ofs < 512; ofs <<= 1) {
      int v = (tid >= ofs) ? sc[tid - ofs] : 0; __syncthreads();
      sc[tid] += v; __syncthreads();
    }
    int incl = sc[tid], excl = incl - segsum;
    if (excl < target && target <= incl) {
      int run = excl;
      for (int j = 0; j < 4; ++j) {
        int h = hist[tid * 4 + j];
        if (run < target && target <= run + h) { bsel[0] = tid * 4 + j; bsel[1] = target - run; }
        run += h;
      }
    }
    __syncthreads();
    pfx = ((unsigned int)bsel[0]) << 21; target = bsel[1];
  }
  __syncthreads();

  // ---- Level B: bits [10,21) ----
  for (int u = tid; u < 2048; u += 512) hist[u] = 0;
  __syncthreads();
  for (int t = tid; t < cnt; t += 512) {
    unsigned int k = keys[t];
    if ((k >> 21) == (pfx >> 21)) atomicAdd(&hist[(k >> 10) & 0x7FF], 1);
  }
  __syncthreads();
  {
    int segsum = 0;
#pragma unroll
    for (int j = 0; j < 4; ++j) segsum += hist[tid * 4 + j];
    sc[tid] = segsum; __syncthreads();
    for (int ofs = 1; ofs < 512; ofs <<= 1) {
      int v = (tid >= ofs) ? sc[tid - ofs] : 0; __syncthreads();
      sc[tid] += v; __syncthreads();
    }
    int incl = sc[tid], excl = incl - segsum;
    if (excl < target && target <= incl) {
      int run = excl;
      for (int j = 0; j < 4; ++j) {
        int h = hist[tid * 4 + j];
        if (run < target && target <= run + h) { bsel[0] = tid * 4 + j; bsel[1] = target - run; }
        run += h;
      }
    }
    __syncthreads();
    pfx |= ((unsigned int)bsel[0]) << 10; target = bsel[1];
  }
  __syncthreads();

  // ---- Level C: bits [0,10) ----
  for (int u = tid; u < 1024; u += 512) hist[u] = 0;
  __syncthreads();
  for (int t = tid; t < cnt; t += 512) {
    unsigned int k = keys[t];
    if ((k >> 10) == (pfx >> 10)) atomicAdd(&hist[k & 0x3FF], 1);
  }
  __syncthreads();
  {
    int segsum = hist[tid * 2] + hist[tid * 2 + 1];
    sc[tid] = segsum; __syncthreads();
    for (int ofs = 1; ofs < 512; ofs <<= 1) {
      int v = (tid >= ofs) ? sc[tid - ofs] : 0; __syncthreads();
      sc[tid] += v; __syncthreads();
    }
    int incl = sc[tid], excl = incl - segsum;
    if (excl < target && target <= incl) {
      int run = excl;
      for (int j = 0; j < 2; ++j) {
        int h = hist[tid * 2 + j];
        if (run < target && target <= run + h) { bsel[0] = tid * 2 + j; }
        run += h;
      }
    }
    __syncthreads();
  }
  unsigned int T = pfx | (unsigned int)bsel[0];
  float fT = __uint_as_float(T ^ inv);
  __syncthreads();

  int nl = 0; float sl = 0.f;
  for (int t = tid; t < cnt; t += 512) {
    unsigned int k = keys[t];
    if (k < T) { nl++; sl += __uint_as_float(k ^ inv); }
  }
  sc[tid] = nl; fred[tid] = sl; __syncthreads();
  for (int st = 256; st > 0; st >>= 1) {
    if (tid < st) { sc[tid] += sc[tid + st]; fred[tid] += fred[tid + st]; }
    __syncthreads();
  }
  int n_less = sc[0];
  float mean = (fred[0] + (float)(KSEL - n_less) * fT) / (float)KSEL;
  __syncthreads();

  float sv = 0.f;
  for (int t = tid; t < cnt; t += 512) {
    unsigned int k = keys[t];
    if (k < T) { float d = __uint_as_float(k ^ inv) - mean; sv += d * d; }
  }
  fred[tid] = sv; __syncthreads();
  for (int st = 256; st > 0; st >>= 1) {
    if (tid < st) fred[tid] += fred[tid + st];
    __syncthreads();
  }
  if (tid == 0) {
    float dT = fT - mean;
    float var = (fred[0] + (float)(KSEL - n_less) * dT * dT) / (float)(KSEL - 1);
    if (largest) pos_stat[ci] = mean + 1.96f * sqrtf(var);
    else neg_stat[ci * 16 + cl] = mean - 1.96f * sqrtf(var);
  }
}

__global__ void __launch_bounds__(256) k_loss(const float* __restrict__ pos_stat,
                                              const float* __restrict__ neg_stat,
                                              float* __restrict__ out) {
  __shared__ float red[256];
  int t = threadIdx.x;
  int i = t >> 4, c = t & 15;
  float v = 0.f;
  if (i != c) v = fmaxf(1.0f + pos_stat[i] - neg_stat[t], 0.f);
  red[t] = v; __syncthreads();
  for (int st = 128; st > 0; st >>= 1) { if (t < st) red[t] += red[t + st]; __syncthreads(); }
  if (t == 0) out[0] = red[0];
}

extern "C" void kernel_launch(void* const* d_in, const int* in_sizes, int n_in,
                              void* d_out, int out_size, void* d_ws, size_t ws_size,
                              hipStream_t stream) {
  const float* x = (const float*)d_in[0];
  const int* y = (const int*)d_in[1];
  float* out = (float*)d_out;
  char* ws = (char*)d_ws;

  float* sums = (float*)(ws + 0);
  int* counts = (int*)(ws + 16384);
  int* offsets = (int*)(ws + 16512);
  float* csq = (float*)(ws + 16576);
  float* pos_stat = (float*)(ws + 16640);
  float* neg_stat = (float*)(ws + 16704);
  float* centers = (float*)(ws + 17728);
  int* bhist = (int*)(ws + 34112);
  float* Dmat = (float*)(ws + 65536);

  hipMemsetAsync(ws, 0, 16512, stream);  // sums + counts
  k_accum<<<1024, 256, 0, stream>>>(x, y, sums, counts);
  k_centers<<<1, 256, 0, stream>>>(sums, counts, centers, csq, offsets);
  k_hist<<<256, 256, 0, stream>>>(y, bhist);
  k_scan<<<1, 256, 0, stream>>>(offsets, bhist);
  k_dist<<<2048, 256, 0, stream>>>(x, y, centers, csq, bhist, Dmat);
  k_select<<<256, 512, 0, stream>>>(Dmat, counts, offsets, pos_stat, neg_stat);
  k_loss<<<1, 256, 0, stream>>>(pos_stat, neg_stat, out);
}

// Round 12
// 112.507 us; speedup vs baseline: 1.5803x; 1.0397x over previous
//
#include <hip/hip_runtime.h>
#include <cfloat>
#include <cstdint>

#define NPTS 65536
#define DIM 256
#define NC 16
#define KSEL 2048
#define VMAX 4608
#define EPSV 1e-6f

// ws layout (bytes):
//     0 : float sums[16*256]   (16384)
// 16384 : int counts[16]       (64)
// 16512 : int offsets[16]      (64)
// 16576 : float csq[16]        (64)
// 16640 : float pos_stat[16]   (64)
// 16704 : float neg_stat[256]  (1024)
// 17728 : float centers[4096]  (16384)
// 34112 : int bhist[256*16]    (16384)
// 65536 : float Dmat[16*65536] (4 MB)  -- ALSO reused as partials[256][4096] by k_accum/k_reduce
//                                         (consumed before k_dist writes Dmat)

__global__ void __launch_bounds__(256) k_hist(const int* __restrict__ y,
                                              int* __restrict__ bhist) {
  __shared__ int h[NC];
  int t = threadIdx.x;
  if (t < NC) h[t] = 0;
  __syncthreads();
  int p = blockIdx.x * 256 + t;
  atomicAdd(&h[y[p * 3 + 2]], 1);
  __syncthreads();
  if (t < NC) bhist[blockIdx.x * NC + t] = h[t];
}

// Scan bhist per class across 256 chunks; also emits counts[] and offsets[].
__global__ void __launch_bounds__(256) k_scan(int* __restrict__ bhist,
                                              int* __restrict__ counts,
                                              int* __restrict__ offsets) {
  __shared__ int lh[256 * NC];
  __shared__ int segbase[16][NC];
  __shared__ int totl[NC], offl[NC];
  int t = threadIdx.x;
  for (int u = t; u < 256 * NC; u += 256) lh[u] = bhist[u];
  __syncthreads();
  int c = t & 15, g = t >> 4;
  int part = 0;
#pragma unroll
  for (int b = 0; b < 16; ++b) part += lh[(g * 16 + b) * NC + c];
  segbase[g][c] = part;
  __syncthreads();
  if (t < NC) {
    int tot = 0;
#pragma unroll
    for (int g2 = 0; g2 < 16; ++g2) tot += segbase[g2][t];
    totl[t] = tot;
    counts[t] = tot;
  }
  __syncthreads();
  if (t == 0) {
    int run = 0;
    for (int c2 = 0; c2 < NC; ++c2) { offl[c2] = run; offsets[c2] = run; run += totl[c2]; }
  }
  __syncthreads();
  if (t < NC) {
    int run = offl[t];
#pragma unroll
    for (int g2 = 0; g2 < 16; ++g2) { int tmp = segbase[g2][t]; segbase[g2][t] = run; run += tmp; }
  }
  __syncthreads();
  int run = segbase[g][c];
#pragma unroll
  for (int b = 0; b < 16; ++b) {
    int idx = (g * 16 + b) * NC + c;
    int tmp = lh[idx]; lh[idx] = run; run += tmp;
  }
  __syncthreads();
  for (int u = t; u < 256 * NC; u += 256) bhist[u] = lh[u];
}

#define ACC_CASE(C) case C: acc[C][0] += xv[u].x; acc[C][1] += xv[u].y; \
                            acc[C][2] += xv[u].z; acc[C][3] += xv[u].w; break;

// 256 blocks x 256 rows. Wave = row-group (64 rows); lane m owns dims [4m,4m+4).
// Label is wave-uniform per row -> readfirstlane + scalar switch: 4 v_add/row.
// Partials to global (coalesced stores) -- no atomics anywhere.
__global__ void __launch_bounds__(256) k_accum(const float* __restrict__ x,
                                               const int* __restrict__ y,
                                               float* __restrict__ partials) {
  __shared__ int labs[256];
  __shared__ float red[4 * NC * DIM];  // 64 KB
  int t = threadIdx.x;
  int n0 = blockIdx.x * 256;
  labs[t] = y[(n0 + t) * 3 + 2];
  __syncthreads();
  int g = t >> 6, m = t & 63;

  float acc[NC][4];
#pragma unroll
  for (int c = 0; c < NC; ++c)
#pragma unroll
    for (int j = 0; j < 4; ++j) acc[c][j] = 0.f;

  for (int i0 = 0; i0 < 64; i0 += 8) {
    float4 xv[8];
#pragma unroll
    for (int u = 0; u < 8; ++u)
      xv[u] = *(const float4*)(x + (size_t)(n0 + g * 64 + i0 + u) * DIM + m * 4);
#pragma unroll
    for (int u = 0; u < 8; ++u) {
      int lab = __builtin_amdgcn_readfirstlane(labs[g * 64 + i0 + u]);
      switch (lab) {
        ACC_CASE(0) ACC_CASE(1) ACC_CASE(2) ACC_CASE(3)
        ACC_CASE(4) ACC_CASE(5) ACC_CASE(6) ACC_CASE(7)
        ACC_CASE(8) ACC_CASE(9) ACC_CASE(10) ACC_CASE(11)
        ACC_CASE(12) ACC_CASE(13) ACC_CASE(14) ACC_CASE(15)
      }
    }
  }

#pragma unroll
  for (int c = 0; c < NC; ++c)
#pragma unroll
    for (int j = 0; j < 4; ++j)
      red[g * (NC * DIM) + c * DIM + m * 4 + j] = acc[c][j];
  __syncthreads();
  for (int u = t; u < NC * DIM; u += 256) {
    float s = red[u] + red[NC * DIM + u] + red[2 * NC * DIM + u] + red[3 * NC * DIM + u];
    partials[(size_t)blockIdx.x * (NC * DIM) + u] = s;
  }
}

__global__ void __launch_bounds__(256) k_reduce(const float* __restrict__ partials,
                                                float* __restrict__ gsums) {
  int u = blockIdx.x * 256 + threadIdx.x;  // 16 blocks -> 4096 outputs
  float s = 0.f;
#pragma unroll 8
  for (int b = 0; b < 256; ++b) s += partials[(size_t)b * (NC * DIM) + u];
  gsums[u] = s;
}

__global__ void __launch_bounds__(256) k_centers(const float* __restrict__ gsums,
                                                 const int* __restrict__ gcounts,
                                                 float* __restrict__ centers,
                                                 float* __restrict__ csq) {
  __shared__ float red[DIM];
  int d = threadIdx.x;
  float v[NC];
#pragma unroll
  for (int c = 0; c < NC; ++c) {
    v[c] = gsums[c * DIM + d] / (float)gcounts[c] + EPSV;
    centers[c * DIM + d] = v[c];
  }
#pragma unroll 1
  for (int c = 0; c < NC; ++c) {
    red[d] = v[c] * v[c];
    __syncthreads();
    for (int st = 128; st > 0; st >>= 1) {
      if (d < st) red[d] += red[d + st];
      __syncthreads();
    }
    if (d == 0) csq[c] = red[0];
    __syncthreads();
  }
}

__global__ void __launch_bounds__(256) k_dist(const float* __restrict__ x,
                                              const int* __restrict__ y,
                                              const float* __restrict__ centers,
                                              const float* __restrict__ csq,
                                              const int* __restrict__ bbase,
                                              float* __restrict__ Dmat) {
  __shared__ float4 cc[NC * 64];
  __shared__ float csql[NC];
  __shared__ int labs[256];
  int t = threadIdx.x;
  const float4* cptr = (const float4*)centers;
  for (int u = t; u < NC * 64; u += 256) {
    int q = u & 63;
    int qs = (q & 0x38) | ((q & 7) ^ ((q >> 3) & 7));
    cc[(u & ~63) | qs] = cptr[u];
  }
  if (t < NC) csql[t] = csq[t];
  int chunk = blockIdx.x >> 3;
  int sub = blockIdx.x & 7;
  labs[t] = y[(chunk * 256 + t) * 3 + 2];
  __syncthreads();

  int pl = sub * 32 + (t >> 3);
  int p = chunk * 256 + pl;
  int s = t & 7;
  const float4* xp = (const float4*)(x + (size_t)p * DIM) + s * 8;
  float4 xv[8];
#pragma unroll
  for (int j = 0; j < 8; ++j) xv[j] = xp[j];
  float xsq = 0.f;
#pragma unroll
  for (int j = 0; j < 8; ++j)
    xsq += xv[j].x * xv[j].x + xv[j].y * xv[j].y + xv[j].z * xv[j].z + xv[j].w * xv[j].w;

  float acc[NC];
#pragma unroll
  for (int i = 0; i < NC; ++i) acc[i] = 0.f;
#pragma unroll
  for (int i = 0; i < NC; ++i) {
#pragma unroll
    for (int j = 0; j < 8; ++j) {
      float4 cv = cc[i * 64 + s * 8 + (j ^ s)];
      acc[i] += xv[j].x * cv.x + xv[j].y * cv.y + xv[j].z * cv.z + xv[j].w * cv.w;
    }
  }

#pragma unroll
  for (int m = 1; m < 8; m <<= 1) {
    xsq += __shfl_xor(xsq, m);
#pragma unroll
    for (int i = 0; i < NC; ++i) acc[i] += __shfl_xor(acc[i], m);
  }

  if (s == 0) {
    int lab = labs[pl];
    int rank = 0;
    for (int q = 0; q < pl; ++q) rank += (labs[q] == lab);
    int base = bbase[chunk * NC + lab] + rank;
#pragma unroll
    for (int i = 0; i < NC; ++i) {
      float d2 = csql[i] - 2.f * acc[i] + xsq;
      Dmat[(size_t)i * NPTS + base] = sqrtf(fmaxf(d2, 0.f));
    }
  }
}

// Radix-select (exact K-th order statistic via 11+11+10-bit LDS histograms),
// then two-pass mean/var over {key < T} + exact-tie correction.
__global__ void __launch_bounds__(512) k_select(const float* __restrict__ Dmat,
                                                const int* __restrict__ gcounts,
                                                const int* __restrict__ offsets,
                                                float* __restrict__ pos_stat,
                                                float* __restrict__ neg_stat) {
  __shared__ unsigned int keys[VMAX];
  __shared__ int hist[2048];
  __shared__ int sc[512];
  __shared__ float fred[512];
  __shared__ int bsel[2];
  int tid = threadIdx.x;
  int b = blockIdx.x;
  int ci = b >> 4, cl = b & 15;
  bool largest = (ci == cl);
  int cnt = gcounts[cl];
  if (cnt > VMAX) cnt = VMAX;
  int off = offsets[cl];
  const float* src = Dmat + (size_t)ci * NPTS + off;
  unsigned int inv = largest ? 0xFFFFFFFFu : 0u;
  for (int t = tid; t < cnt; t += 512) keys[t] = __float_as_uint(src[t]) ^ inv;
  __syncthreads();

  int target = KSEL;
  unsigned int pfx = 0;

  // ---- Level A: bits [21,32) ----
  for (int u = tid; u < 2048; u += 512) hist[u] = 0;
  __syncthreads();
  for (int t = tid; t < cnt; t += 512) atomicAdd(&hist[keys[t] >> 21], 1);
  __syncthreads();
  {
    int segsum = 0;
#pragma unroll
    for (int j = 0; j < 4; ++j) segsum += hist[tid * 4 + j];
    sc[tid] = segsum; __syncthreads();
    for (int ofs = 1; ofs < 512; ofs <<= 1) {
      int v = (tid >= ofs) ? sc[tid - ofs] : 0; __syncthreads();
      sc[tid] += v; __syncthreads();
    }
    int incl = sc[tid], excl = incl - segsum;
    if (excl < target && target <= incl) {
      int run = excl;
      for (int j = 0; j < 4; ++j) {
        int h = hist[tid * 4 + j];
        if (run < target && target <= run + h) { bsel[0] = tid * 4 + j; bsel[1] = target - run; }
        run += h;
      }
    }
    __syncthreads();
    pfx = ((unsigned int)bsel[0]) << 21; target = bsel[1];
  }
  __syncthreads();

  // ---- Level B: bits [10,21) ----
  for (int u = tid; u < 2048; u += 512) hist[u] = 0;
  __syncthreads();
  for (int t = tid; t < cnt; t += 512) {
    unsigned int k = keys[t];
    if ((k >> 21) == (pfx >> 21)) atomicAdd(&hist[(k >> 10) & 0x7FF], 1);
  }
  __syncthreads();
  {
    int segsum = 0;
#pragma unroll
    for (int j = 0; j < 4; ++j) segsum += hist[tid * 4 + j];
    sc[tid] = segsum; __syncthreads();
    for (int ofs = 1; ofs < 512; ofs <<= 1) {
      int v = (tid >= ofs) ? sc[tid - ofs] : 0; __syncthreads();
      sc[tid] += v; __syncthreads();
    }
    int incl = sc[tid], excl = incl - segsum;
    if (excl < target && target <= incl) {
      int run = excl;
      for (int j = 0; j < 4; ++j) {
        int h = hist[tid * 4 + j];
        if (run < target && target <= run + h) { bsel[0] = tid * 4 + j; bsel[1] = target - run; }
        run += h;
      }
    }
    __syncthreads();
    pfx |= ((unsigned int)bsel[0]) << 10; target = bsel[1];
  }
  __syncthreads();

  // ---- Level C: bits [0,10) ----
  for (int u = tid; u < 1024; u += 512) hist[u] = 0;
  __syncthreads();
  for (int t = tid; t < cnt; t += 512) {
    unsigned int k = keys[t];
    if ((k >> 10) == (pfx >> 10)) atomicAdd(&hist[k & 0x3FF], 1);
  }
  __syncthreads();
  {
    int segsum = hist[tid * 2] + hist[tid * 2 + 1];
    sc[tid] = segsum; __syncthreads();
    for (int ofs = 1; ofs < 512; ofs <<= 1) {
      int v = (tid >= ofs) ? sc[tid - ofs] : 0; __syncthreads();
      sc[tid] += v; __syncthreads();
    }
    int incl = sc[tid], excl = incl - segsum;
    if (excl < target && target <= incl) {
      int run = excl;
      for (int j = 0; j < 2; ++j) {
        int h = hist[tid * 2 + j];
        if (run < target && target <= run + h) { bsel[0] = tid * 2 + j; }
        run += h;
      }
    }
    __syncthreads();
  }
  unsigned int T = pfx | (unsigned int)bsel[0];
  float fT = __uint_as_float(T ^ inv);
  __syncthreads();

  int nl = 0; float sl = 0.f;
  for (int t = tid; t < cnt; t += 512) {
    unsigned int k = keys[t];
    if (k < T) { nl++; sl += __uint_as_float(k ^ inv); }
  }
  sc[tid] = nl; fred[tid] = sl; __syncthreads();
  for (int st = 256; st > 0; st >>= 1) {
    if (tid < st) { sc[tid] += sc[tid + st]; fred[tid] += fred[tid + st]; }
    __syncthreads();
  }
  int n_less = sc[0];
  float mean = (fred[0] + (float)(KSEL - n_less) * fT) / (float)KSEL;
  __syncthreads();

  float sv = 0.f;
  for (int t = tid; t < cnt; t += 512) {
    unsigned int k = keys[t];
    if (k < T) { float d = __uint_as_float(k ^ inv) - mean; sv += d * d; }
  }
  fred[tid] = sv; __syncthreads();
  for (int st = 256; st > 0; st >>= 1) {
    if (tid < st) fred[tid] += fred[tid + st];
    __syncthreads();
  }
  if (tid == 0) {
    float dT = fT - mean;
    float var = (fred[0] + (float)(KSEL - n_less) * dT * dT) / (float)(KSEL - 1);
    if (largest) pos_stat[ci] = mean + 1.96f * sqrtf(var);
    else neg_stat[ci * 16 + cl] = mean - 1.96f * sqrtf(var);
  }
}

__global__ void __launch_bounds__(256) k_loss(const float* __restrict__ pos_stat,
                                              const float* __restrict__ neg_stat,
                                              float* __restrict__ out) {
  __shared__ float red[256];
  int t = threadIdx.x;
  int i = t >> 4, c = t & 15;
  float v = 0.f;
  if (i != c) v = fmaxf(1.0f + pos_stat[i] - neg_stat[t], 0.f);
  red[t] = v; __syncthreads();
  for (int st = 128; st > 0; st >>= 1) { if (t < st) red[t] += red[t + st]; __syncthreads(); }
  if (t == 0) out[0] = red[0];
}

extern "C" void kernel_launch(void* const* d_in, const int* in_sizes, int n_in,
                              void* d_out, int out_size, void* d_ws, size_t ws_size,
                              hipStream_t stream) {
  const float* x = (const float*)d_in[0];
  const int* y = (const int*)d_in[1];
  float* out = (float*)d_out;
  char* ws = (char*)d_ws;

  float* sums = (float*)(ws + 0);
  int* counts = (int*)(ws + 16384);
  int* offsets = (int*)(ws + 16512);
  float* csq = (float*)(ws + 16576);
  float* pos_stat = (float*)(ws + 16640);
  float* neg_stat = (float*)(ws + 16704);
  float* centers = (float*)(ws + 17728);
  int* bhist = (int*)(ws + 34112);
  float* Dmat = (float*)(ws + 65536);
  float* partials = (float*)(ws + 65536);  // reuses Dmat region, consumed before k_dist

  k_hist<<<256, 256, 0, stream>>>(y, bhist);
  k_scan<<<1, 256, 0, stream>>>(bhist, counts, offsets);
  k_accum<<<256, 256, 0, stream>>>(x, y, partials);
  k_reduce<<<16, 256, 0, stream>>>(partials, sums);
  k_centers<<<1, 256, 0, stream>>>(sums, counts, centers, csq);
  k_dist<<<2048, 256, 0, stream>>>(x, y, centers, csq, bhist, Dmat);
  k_select<<<256, 512, 0, stream>>>(Dmat, counts, offsets, pos_stat, neg_stat);
  k_loss<<<1, 256, 0, stream>>>(pos_stat, neg_stat, out);
}